// Round 4
// baseline (346.190 us; speedup 1.0000x reference)
//
#include <hip/hip_runtime.h>
#include <hip/hip_bf16.h>

// tokens[bn,t] = mask[bn] ? (cat[bn,:]·W[t,:] + b[t]) : 0 ; M=16384, K=3133, T=256
// R4: amortize barrier-drain latency (R3 was ~95us: 49 barriers x full vmcnt(0)
//     drain with only 2 waves/SIMD of TLP).
//  - 4 LDS W-buffers (64KB), group = 2 steps, barrier per GROUP (25 vs 49);
//    stage(group g+2) issued right AFTER the barrier that frees its buffers ->
//    every load has ~2 steps of compute in flight before its draining barrier.
//  - A loads: hoisted mask pointer-select (masked lanes read emb row 0; garbage
//    only reaches masked output rows, which epilogue forces to 0). Branch-free
//    group-level prefetch (Aa/Ab regsets, compile-time indexed via parity unroll).
//  - K padded to 50 steps: 48 emb + 1 ext + 1 zero-W step.

#define TOKENS   16384
#define EMB      3072
#define KF       3133
#define TDIM     256
#define NS       50      // padded steps (W image for s=49 is zeros)
#define BM       64
#define BT       128
#define WIMG     16384   // bytes per (ttile,step) W image: 128 rows x 64 cols bf16

typedef __attribute__((ext_vector_type(8))) short bf16x8;
typedef __attribute__((ext_vector_type(4))) float f32x4;

__device__ __forceinline__ unsigned int f2bf(float f) {
  __hip_bfloat16 h = __float2bfloat16(f);
  unsigned short u;
  __builtin_memcpy(&u, &h, 2);
  return (unsigned int)u;
}
__device__ __forceinline__ unsigned int pack2(float a, float b) {
  return f2bf(a) | (f2bf(b) << 16);
}
__device__ __forceinline__ bf16x8 cvt8(float4 a, float4 b) {
  union { unsigned int u[4]; bf16x8 v; } r;
  r.u[0] = pack2(a.x, a.y);
  r.u[1] = pack2(a.z, a.w);
  r.u[2] = pack2(b.x, b.y);
  r.u[3] = pack2(b.z, b.w);
  return r.v;
}

__device__ __forceinline__ void g2l16(const void* g, void* l) {
  __builtin_amdgcn_global_load_lds(
      (__attribute__((address_space(1))) void*)g,
      (__attribute__((address_space(3))) void*)l,
      16, 0, 0);
}

// W prepack: wq[tt][s][row][c'] (bf16), c' = c ^ ((row&7)<<3), row-major 128x64.
// Byte-for-byte the linear LDS image stageW() DMAs in. s>=49 -> zeros (k>=KF).
__global__ void pack_w_kernel(const float* __restrict__ W, unsigned short* __restrict__ wq) {
  int i = blockIdx.x * 256 + threadIdx.x;   // 2*NS*8192 = 819200 total
  if (i >= 2 * NS * 8192) return;
  int tt  = i / (NS * 8192);
  int r   = i % (NS * 8192);
  int s   = r >> 13;
  int e   = r & 8191;
  int row = e >> 6;
  int cs  = e & 63;
  int c   = cs ^ ((row & 7) << 3);
  int k   = s * 64 + c;
  int t   = tt * BT + row;
  float v = (k < KF) ? W[(size_t)t * KF + k] : 0.f;
  __hip_bfloat16 h = __float2bfloat16(v);
  unsigned short u; __builtin_memcpy(&u, &h, 2);
  wq[i] = u;
}

__global__ void pack_ext_kernel(const float* __restrict__ vis,
                                const float* __restrict__ bbox,
                                const float* __restrict__ kpt,
                                float* __restrict__ ext) {
  int i = blockIdx.x * 256 + threadIdx.x;   // TOKENS*64
  int bn = i >> 6;
  int j  = i & 63;
  float v = 0.f;
  if (j < 6)       v = vis[bn * 6 + j];
  else if (j < 10) v = bbox[bn * 4 + (j - 6)];
  else if (j < 61) v = kpt[bn * 51 + (j - 10)];
  ext[i] = v;
}

__global__ __launch_bounds__(256, 2)
void linproj_kernel(const float* __restrict__ emb,
                    const int* __restrict__ mask,
                    const unsigned short* __restrict__ wqp,
                    const float* __restrict__ ext,
                    const float* __restrict__ bias,
                    float* __restrict__ out) {
  __shared__ unsigned short ldsW[4 * 8192];   // 4 x 16KB: step s -> buf s&3

  const int tid = threadIdx.x;
  const int bid = blockIdx.x;
  // XCD swizzle: both ttiles of an mtile on the same XCD (A L2/L3 reuse)
  const int mtile = ((bid >> 4) << 3) | (bid & 7);
  const int ttile = (bid >> 3) & 1;
  const int mBase = mtile * BM;
  const int tBase = ttile * BT;

  const int lane = tid & 63;
  const int wid  = tid >> 6;        // 0..3
  const int wm   = (wid >> 1) * 32;
  const int wt   = (wid & 1) * 64;
  const int lr   = lane & 15;
  const int lk   = lane >> 4;       // 0..3

  // ---- A pointers (hoisted mask select; masked lanes -> emb row 0 / ext row 0) ----
  const int row0 = mBase + wm + lr;
  const int row1 = row0 + 16;
  const bool m0 = (mask[row0] != 0);
  const bool m1 = (mask[row1] != 0);
  const int aoff = lk * 8;
  const float* pA0 = (m0 ? emb + (size_t)row0 * EMB : emb) + aoff;
  const float* pA1 = (m1 ? emb + (size_t)row1 * EMB : emb) + aoff;
  const float* pE0 = (m0 ? ext + (size_t)row0 * 64 : ext) + aoff;
  const float* pE1 = (m1 ? ext + (size_t)row1 * 64 : ext) + aoff;

  // ---- W staging ----
  const char* wsrc = (const char*)wqp + (size_t)ttile * (NS * WIMG)
                   + wid * 1024 + lane * 16;
  char* lbase = (char*)ldsW;

  // ---- swizzled ds_read offsets ----
  const int swz0 = (lk * 16) ^ ((lr & 7) << 4);
  const int swz1 = (64 + lk * 16) ^ ((lr & 7) << 4);
  const int rbase = (wt + lr) * 128;

  f32x4 acc[2][4];
#pragma unroll
  for (int m = 0; m < 2; ++m)
#pragma unroll
    for (int t = 0; t < 4; ++t)
      acc[m][t] = (f32x4){0.f, 0.f, 0.f, 0.f};

  float4 Aa[2][2][2][2], Ab[2][2][2][2];   // [step][rowgrp][kk][half]

  auto stageW = [&](int s, int buf) {
    const char* g = wsrc + (size_t)s * WIMG;
    char* l = lbase + buf * WIMG + wid * 1024;
#pragma unroll
    for (int j = 0; j < 4; ++j)
      g2l16(g + j * 4096, l + j * 4096);
  };
  auto stage2 = [&](int s0, int bp) {      // group of 2 steps -> buf pair bp
    if (s0 < NS) { stageW(s0, bp * 2); stageW(s0 + 1, bp * 2 + 1); }
  };

  auto loadA2 = [&](int s0, float4 (&A)[2][2][2][2]) {
#pragma unroll
    for (int st = 0; st < 2; ++st) {
      const int s = s0 + st;
      const float* q0 = (s < NS - 2) ? (pA0 + s * 64) : pE0;
      const float* q1 = (s < NS - 2) ? (pA1 + s * 64) : pE1;
#pragma unroll
      for (int kk = 0; kk < 2; ++kk) {
        A[st][0][kk][0] = *(const float4*)(q0 + kk * 32);
        A[st][0][kk][1] = *(const float4*)(q0 + kk * 32 + 4);
        A[st][1][kk][0] = *(const float4*)(q1 + kk * 32);
        A[st][1][kk][1] = *(const float4*)(q1 + kk * 32 + 4);
      }
    }
  };

  auto computeStep = [&](int b, const float4 (&A)[2][2][2]) {
    const char* l = lbase + b * WIMG;
#pragma unroll
    for (int kk = 0; kk < 2; ++kk) {
      bf16x8 a0 = cvt8(A[0][kk][0], A[0][kk][1]);
      bf16x8 a1 = cvt8(A[1][kk][0], A[1][kk][1]);
      const int sw = kk ? swz1 : swz0;
#pragma unroll
      for (int tf = 0; tf < 4; ++tf) {
        bf16x8 bv = *(const bf16x8*)(l + rbase + tf * 2048 + sw);
        acc[0][tf] = __builtin_amdgcn_mfma_f32_16x16x32_bf16(a0, bv, acc[0][tf], 0, 0, 0);
        acc[1][tf] = __builtin_amdgcn_mfma_f32_16x16x32_bf16(a1, bv, acc[1][tf], 0, 0, 0);
      }
    }
  };

  // prologue: stage groups 0,1 (bufs 0-3), load A for group 0
  stage2(0, 0);
  stage2(2, 1);
  loadA2(0, Aa);
  __syncthreads();

  // 25 groups; parity-unrolled pairs for compile-time buffers/regsets
#pragma unroll 1
  for (int g = 0; g < 24; g += 2) {
    // group g (even): bufs 0,1; cur=Aa, prefetch group g+1 -> Ab
    loadA2(2 * g + 2, Ab);
    computeStep(0, Aa[0]);
    computeStep(1, Aa[1]);
    __syncthreads();                 // frees bufs 0,1; drains their next stage later
    stage2(2 * g + 4, 0);            // group g+2 -> bufs 0,1
    // group g+1 (odd): bufs 2,3; cur=Ab, prefetch group g+2 -> Aa
    loadA2(2 * g + 4, Aa);
    computeStep(2, Ab[0]);
    computeStep(3, Ab[1]);
    __syncthreads();                 // frees bufs 2,3
    stage2(2 * g + 6, 1);            // group g+3 -> bufs 2,3
  }
  // final group 24 (steps 48,49): bufs 0,1, regs Aa (loaded in last odd body)
  computeStep(0, Aa[0]);
  computeStep(1, Aa[1]);

  // epilogue: D col = lane&15 (t), row = (lane>>4)*4 + r (m)
#pragma unroll
  for (int tf = 0; tf < 4; ++tf) {
    const int t = tBase + wt + tf * 16 + lr;
    const float bv = bias[t];
#pragma unroll
    for (int mf = 0; mf < 2; ++mf) {
#pragma unroll
      for (int r = 0; r < 4; ++r) {
        const int bn = mBase + wm + mf * 16 + lk * 4 + r;
        out[(size_t)bn * TDIM + t] = (mask[bn] != 0) ? (acc[mf][tf][r] + bv) : 0.f;
      }
    }
  }
}

extern "C" void kernel_launch(void* const* d_in, const int* in_sizes, int n_in,
                              void* d_out, int out_size, void* d_ws, size_t ws_size,
                              hipStream_t stream) {
  const float* emb   = (const float*)d_in[0];
  const float* vis   = (const float*)d_in[1];
  const float* bbox  = (const float*)d_in[2];
  const float* kpt   = (const float*)d_in[3];
  const int*   mask  = (const int*)d_in[4];   // jnp.bool_ -> int32 per harness contract
  const float* W     = (const float*)d_in[5];
  const float* bias  = (const float*)d_in[6];
  float* out = (float*)d_out;

  // ws: [ ext f32 16384*64 = 4MB ][ wq bf16 2*50*8192 = 1.6MB ]
  float* ext          = (float*)d_ws;
  unsigned short* wq  = (unsigned short*)((char*)d_ws + (size_t)TOKENS * 64 * 4);

  pack_w_kernel  <<<(2 * NS * 8192 + 255) / 256, 256, 0, stream>>>(W, wq);
  pack_ext_kernel<<<(TOKENS * 64) / 256,         256, 0, stream>>>(vis, bbox, kpt, ext);
  linproj_kernel <<<512, 256, 0, stream>>>(emb, mask, wq, ext, bias, out);
}